// Round 1
// baseline (717.801 us; speedup 1.0000x reference)
//
#include <hip/hip_runtime.h>
#include <math.h>

#define BDIM 512
#define EDIM 4096
#define KDIM 1024
#define MDIM 1024
#define LDIM 32
#define TOPK 4
#define EPSF 1e-12f

// ---------------------------------------------------------------------------
// Tiled fp32 NT-GEMM: C[i,j] = sum_k A[i*Kd+k] * Bm[j*Kd+k]
// Optional epilogue scaling: C *= 1/(max(rnA[i],eps)*max(rnB[j],eps))
// Tile 64x64, K-chunk 32, 256 threads, 4x4 accumulators per thread.
// All dims divide evenly (512/64, 1024/64, 4096/32, 1024/32) -> no bounds checks.
// ---------------------------------------------------------------------------
__global__ __launch_bounds__(256)
void gemm_nt_kernel(const float* __restrict__ A, const float* __restrict__ Bm,
                    float* __restrict__ C, int Ncols, int Kd,
                    const float* __restrict__ rnA, const float* __restrict__ rnB)
{
    __shared__ float As[64][33];
    __shared__ float Bs[64][33];

    const int tid = threadIdx.x;
    const int tx = tid & 15;        // 0..15 -> 4 output cols
    const int ty = tid >> 4;        // 0..15 -> 4 output rows
    const int bi = blockIdx.y * 64; // row block
    const int bj = blockIdx.x * 64; // col block

    float acc[4][4] = {};

    const int lr = tid >> 3;        // 0..31 load row
    const int lc = (tid & 7) * 4;   // 0..28 load col (float4)

    for (int k0 = 0; k0 < Kd; k0 += 32) {
        float4 a0 = *(const float4*)&A[(size_t)(bi + lr)      * Kd + k0 + lc];
        float4 a1 = *(const float4*)&A[(size_t)(bi + lr + 32) * Kd + k0 + lc];
        float4 b0 = *(const float4*)&Bm[(size_t)(bj + lr)      * Kd + k0 + lc];
        float4 b1 = *(const float4*)&Bm[(size_t)(bj + lr + 32) * Kd + k0 + lc];
        As[lr][lc+0] = a0.x; As[lr][lc+1] = a0.y; As[lr][lc+2] = a0.z; As[lr][lc+3] = a0.w;
        As[lr+32][lc+0] = a1.x; As[lr+32][lc+1] = a1.y; As[lr+32][lc+2] = a1.z; As[lr+32][lc+3] = a1.w;
        Bs[lr][lc+0] = b0.x; Bs[lr][lc+1] = b0.y; Bs[lr][lc+2] = b0.z; Bs[lr][lc+3] = b0.w;
        Bs[lr+32][lc+0] = b1.x; Bs[lr+32][lc+1] = b1.y; Bs[lr+32][lc+2] = b1.z; Bs[lr+32][lc+3] = b1.w;
        __syncthreads();

        #pragma unroll
        for (int kk = 0; kk < 32; ++kk) {
            float av[4], bv[4];
            #pragma unroll
            for (int i = 0; i < 4; ++i) av[i] = As[ty*4 + i][kk];
            #pragma unroll
            for (int j = 0; j < 4; ++j) bv[j] = Bs[tx*4 + j][kk];
            #pragma unroll
            for (int i = 0; i < 4; ++i)
                #pragma unroll
                for (int j = 0; j < 4; ++j)
                    acc[i][j] += av[i] * bv[j];
        }
        __syncthreads();
    }

    float sA[4], sB[4];
    #pragma unroll
    for (int i = 0; i < 4; ++i) sA[i] = rnA ? 1.f / fmaxf(rnA[bi + ty*4 + i], EPSF) : 1.f;
    #pragma unroll
    for (int j = 0; j < 4; ++j) sB[j] = rnB ? 1.f / fmaxf(rnB[bj + tx*4 + j], EPSF) : 1.f;

    #pragma unroll
    for (int i = 0; i < 4; ++i) {
        size_t rowoff = (size_t)(bi + ty*4 + i) * Ncols + bj + tx*4;
        #pragma unroll
        for (int j = 0; j < 4; ++j)
            C[rowoff + j] = acc[i][j] * sA[i] * sB[j];
    }
}

// ---------------------------------------------------------------------------
// Row L2-norm: out[row] = sqrt(sum_c X[row,c]^2), ncols must be 1024 here.
// ---------------------------------------------------------------------------
__global__ __launch_bounds__(256)
void rownorm_kernel(const float* __restrict__ X, float* __restrict__ out, int ncols)
{
    const int row = blockIdx.x;
    const float* p = X + (size_t)row * ncols;
    float s = 0.f;
    for (int c = threadIdx.x * 4; c < ncols; c += 256 * 4) {
        float4 v = *(const float4*)(p + c);
        s += v.x*v.x + v.y*v.y + v.z*v.z + v.w*v.w;
    }
    #pragma unroll
    for (int off = 32; off > 0; off >>= 1) s += __shfl_down(s, off, 64);
    __shared__ float wsum[4];
    const int lane = threadIdx.x & 63, wid = threadIdx.x >> 6;
    if (lane == 0) wsum[wid] = s;
    __syncthreads();
    if (threadIdx.x == 0)
        out[row] = sqrtf(wsum[0] + wsum[1] + wsum[2] + wsum[3]);
}

// ---------------------------------------------------------------------------
// Top-4 per row (thread-per-row). Strict > keeps lowest index on ties,
// matching jax.lax.top_k stability. Downstream is permutation-invariant
// in the selected set, so only the SET must match.
// ---------------------------------------------------------------------------
__global__ __launch_bounds__(256)
void topk_kernel(const float* __restrict__ sim, int* __restrict__ topi,
                 float* __restrict__ topv)
{
    const int b = blockIdx.x * blockDim.x + threadIdx.x;
    if (b >= BDIM) return;
    const float* row = sim + (size_t)b * MDIM;
    float v0 = -INFINITY, v1 = -INFINITY, v2 = -INFINITY, v3 = -INFINITY;
    int i0 = 0, i1 = 0, i2 = 0, i3 = 0;
    for (int m = 0; m < MDIM; ++m) {
        float x = row[m];
        if (x > v3) {
            if (x > v2) {
                v3 = v2; i3 = i2;
                if (x > v1) {
                    v2 = v1; i2 = i1;
                    if (x > v0) { v1 = v0; i1 = i0; v0 = x; i0 = m; }
                    else        { v1 = x; i1 = m; }
                } else { v2 = x; i2 = m; }
            } else { v3 = x; i3 = m; }
        }
    }
    topv[b*4+0] = v0; topv[b*4+1] = v1; topv[b*4+2] = v2; topv[b*4+3] = v3;
    topi[b*4+0] = i0; topi[b*4+1] = i1; topi[b*4+2] = i2; topi[b*4+3] = i3;
}

// ---------------------------------------------------------------------------
// Gather + softmax + weighted sum.
// One block per (b,l); 256 threads cover E=4096 as float4 (4 iters).
// ---------------------------------------------------------------------------
__global__ __launch_bounds__(256)
void gather_out_kernel(const float* __restrict__ pm, const int* __restrict__ topi,
                       const float* __restrict__ topv, float* __restrict__ out)
{
    const int bl = blockIdx.x;
    const int b = bl / LDIM, l = bl % LDIM;

    const int j0 = topi[b*4+0], j1 = topi[b*4+1], j2 = topi[b*4+2], j3 = topi[b*4+3];
    const float r0 = topv[b*4+0], r1 = topv[b*4+1], r2 = topv[b*4+2], r3 = topv[b*4+3];
    const float mx = fmaxf(fmaxf(r0, r1), fmaxf(r2, r3));
    const float e0 = expf(r0 - mx), e1 = expf(r1 - mx), e2 = expf(r2 - mx), e3 = expf(r3 - mx);
    const float inv = 1.f / (e0 + e1 + e2 + e3);
    const float w0 = e0*inv, w1 = e1*inv, w2 = e2*inv, w3 = e3*inv;

    const float4* p0 = (const float4*)(pm + ((size_t)j0 * LDIM + l) * EDIM);
    const float4* p1 = (const float4*)(pm + ((size_t)j1 * LDIM + l) * EDIM);
    const float4* p2 = (const float4*)(pm + ((size_t)j2 * LDIM + l) * EDIM);
    const float4* p3 = (const float4*)(pm + ((size_t)j3 * LDIM + l) * EDIM);
    float4* o = (float4*)(out + ((size_t)b * LDIM + l) * EDIM);

    for (int c = threadIdx.x; c < EDIM/4; c += 256) {
        float4 a = p0[c], bb = p1[c], cc = p2[c], dd = p3[c];
        float4 r;
        r.x = w0*a.x + w1*bb.x + w2*cc.x + w3*dd.x;
        r.y = w0*a.y + w1*bb.y + w2*cc.y + w3*dd.y;
        r.z = w0*a.z + w1*bb.z + w2*cc.z + w3*dd.z;
        r.w = w0*a.w + w1*bb.w + w2*cc.w + w3*dd.w;
        o[c] = r;
    }
}

extern "C" void kernel_launch(void* const* d_in, const int* in_sizes, int n_in,
                              void* d_out, int out_size, void* d_ws, size_t ws_size,
                              hipStream_t stream)
{
    const float* x_query = (const float*)d_in[0];      // [B, E]
    const float* W_proj  = (const float*)d_in[1];      // [K, E]
    const float* pm      = (const float*)d_in[2];      // [M, L, E]
    const float* pkeys   = (const float*)d_in[3];      // [M, K]
    float* out = (float*)d_out;                        // [B, L, E]

    // workspace layout (floats)
    float* x_proj = (float*)d_ws;                      // B*K   = 524288
    float* sim    = x_proj + (size_t)BDIM * KDIM;      // B*M   = 524288
    float* xn     = sim    + (size_t)BDIM * MDIM;      // B
    float* kn     = xn + BDIM;                         // M
    float* topv   = kn + MDIM;                         // B*4
    int*   topi   = (int*)(topv + BDIM * TOPK);        // B*4

    // 1. x_proj = x_query @ W_proj^T   [512,1024]
    gemm_nt_kernel<<<dim3(KDIM/64, BDIM/64), 256, 0, stream>>>(
        x_query, W_proj, x_proj, KDIM, EDIM, nullptr, nullptr);

    // 2. row norms of x_proj and prompt_keys
    rownorm_kernel<<<BDIM, 256, 0, stream>>>(x_proj, xn, KDIM);
    rownorm_kernel<<<MDIM, 256, 0, stream>>>(pkeys, kn, KDIM);

    // 3. sim = (x_proj @ pkeys^T) / (max(xn,eps)*max(kn,eps))   [512,1024]
    gemm_nt_kernel<<<dim3(MDIM/64, BDIM/64), 256, 0, stream>>>(
        x_proj, pkeys, sim, MDIM, KDIM, xn, kn);

    // 4. top-4 per row (values are "refined" directly)
    topk_kernel<<<(BDIM + 255)/256, 256, 0, stream>>>(sim, topi, topv);

    // 5. softmax weights + gather + weighted sum -> out [512,32,4096]
    gather_out_kernel<<<BDIM * LDIM, 256, 0, stream>>>(pm, topi, topv, out);
}

// Round 2
// 271.341 us; speedup vs baseline: 2.6454x; 2.6454x over previous
//
#include <hip/hip_runtime.h>
#include <math.h>

#define BDIM 512
#define EDIM 4096
#define KDIM 1024
#define MDIM 1024
#define LDIM 32
#define TOPK 4
#define EPSF 1e-12f

typedef __attribute__((ext_vector_type(8))) short short8;
typedef __attribute__((ext_vector_type(4))) float f32x4;

struct us4 { ushort x, y, z, w; };

__device__ inline ushort f2bf_rn(float x) {
    union { float f; unsigned u; } v; v.f = x;
    unsigned r = (v.u + 0x7FFF + ((v.u >> 16) & 1)) >> 16;
    return (ushort)r;
}
__device__ inline float bf2f(ushort h) {
    union { unsigned u; float f; } v; v.u = ((unsigned)h) << 16;
    return v.f;
}

// ---------------------------------------------------------------------------
// fp32 -> (hi, lo) bf16 split: x ~= hi + lo with ~16-bit mantissa coverage.
// ---------------------------------------------------------------------------
__global__ __launch_bounds__(256)
void split_kernel(const float* __restrict__ x, ushort* __restrict__ hi,
                  ushort* __restrict__ lo, int n4)
{
    for (int i = blockIdx.x * 256 + threadIdx.x; i < n4; i += gridDim.x * 256) {
        float4 v = ((const float4*)x)[i];
        us4 h, l;
        h.x = f2bf_rn(v.x); l.x = f2bf_rn(v.x - bf2f(h.x));
        h.y = f2bf_rn(v.y); l.y = f2bf_rn(v.y - bf2f(h.y));
        h.z = f2bf_rn(v.z); l.z = f2bf_rn(v.z - bf2f(h.z));
        h.w = f2bf_rn(v.w); l.w = f2bf_rn(v.w - bf2f(h.w));
        ((us4*)hi)[i] = h;
        ((us4*)lo)[i] = l;
    }
}

// ---------------------------------------------------------------------------
// Split-bf16 MFMA NT-GEMM: C = A @ B^T with A=[M][K], B=[N][K] fp32 split into
// hi/lo bf16. 3-term: ah*bh + ah*bl + al*bh (al*bl ~ 2^-18, dropped).
// 64x64 tile, BK=32, 256 threads = 4 waves of 32x32 (2x2 16x16x32 frags).
// Split-K over blockIdx.z writing partials Cp[z][M][N].
// LDS rows padded to 40 ushorts (80B): bank-quad = (5*row+g)%8 -> uniform.
// Symmetric 8-contiguous fragment loads for A and B cancel any intra-lane
// k-permutation of the MFMA operand layout; C/D map: col=lane&15,
// row=(lane>>4)*4+reg (HW-verified).
// ---------------------------------------------------------------------------
__global__ __launch_bounds__(256)
void gemm_mfma_split(const ushort* __restrict__ Ah, const ushort* __restrict__ Al,
                     const ushort* __restrict__ Bh, const ushort* __restrict__ Bl,
                     float* __restrict__ Cp, int M, int N, int K, int Kchunk)
{
    __shared__ ushort lds[4][64][40];

    const int t  = threadIdx.x;
    const int bn = blockIdx.x, bm = blockIdx.y, kz = blockIdx.z;

    // staging coords: thread t loads one 16B chunk per tile per k-step
    const int srow = t >> 2, sg = t & 3;
    const size_t aoff = (size_t)(bm * 64 + srow) * K + sg * 8 + (size_t)kz * Kchunk;
    const size_t boff = (size_t)(bn * 64 + srow) * K + sg * 8 + (size_t)kz * Kchunk;

    const int lane = t & 63, wid = t >> 6;
    const int wr = wid >> 1, wc = wid & 1;
    const int fr = lane & 15, fg = lane >> 4;

    f32x4 acc[2][2];
    #pragma unroll
    for (int i = 0; i < 2; ++i)
        #pragma unroll
        for (int j = 0; j < 2; ++j)
            acc[i][j] = (f32x4){0.f, 0.f, 0.f, 0.f};

    for (int k0 = 0; k0 < Kchunk; k0 += 32) {
        *(short8*)(&lds[0][srow][sg * 8]) = *(const short8*)(Ah + aoff + k0);
        *(short8*)(&lds[1][srow][sg * 8]) = *(const short8*)(Al + aoff + k0);
        *(short8*)(&lds[2][srow][sg * 8]) = *(const short8*)(Bh + boff + k0);
        *(short8*)(&lds[3][srow][sg * 8]) = *(const short8*)(Bl + boff + k0);
        __syncthreads();

        short8 ah[2], al[2], bh[2], bl[2];
        #pragma unroll
        for (int i = 0; i < 2; ++i) {
            ah[i] = *(const short8*)(&lds[0][wr * 32 + i * 16 + fr][fg * 8]);
            al[i] = *(const short8*)(&lds[1][wr * 32 + i * 16 + fr][fg * 8]);
            bh[i] = *(const short8*)(&lds[2][wc * 32 + i * 16 + fr][fg * 8]);
            bl[i] = *(const short8*)(&lds[3][wc * 32 + i * 16 + fr][fg * 8]);
        }
        #pragma unroll
        for (int i = 0; i < 2; ++i)
            #pragma unroll
            for (int j = 0; j < 2; ++j) {
                acc[i][j] = __builtin_amdgcn_mfma_f32_16x16x32_bf16(ah[i], bh[j], acc[i][j], 0, 0, 0);
                acc[i][j] = __builtin_amdgcn_mfma_f32_16x16x32_bf16(ah[i], bl[j], acc[i][j], 0, 0, 0);
                acc[i][j] = __builtin_amdgcn_mfma_f32_16x16x32_bf16(al[i], bh[j], acc[i][j], 0, 0, 0);
            }
        __syncthreads();
    }

    float* Cz = Cp + (size_t)kz * M * N;
    #pragma unroll
    for (int i = 0; i < 2; ++i)
        #pragma unroll
        for (int j = 0; j < 2; ++j)
            #pragma unroll
            for (int q = 0; q < 4; ++q) {
                int orow = bm * 64 + wr * 32 + i * 16 + (lane >> 4) * 4 + q;
                int ocol = bn * 64 + wc * 32 + j * 16 + (lane & 15);
                Cz[(size_t)orow * N + ocol] = acc[i][j][q];
            }
}

// ---------------------------------------------------------------------------
// Reduce split-K partials: out[i] = sum_z Cp[z][i]   (float4 granularity)
// ---------------------------------------------------------------------------
__global__ __launch_bounds__(256)
void reduce4_kernel(const float* __restrict__ Cp, float* __restrict__ out,
                    int n4, int nsplit)
{
    int i = blockIdx.x * 256 + threadIdx.x;
    if (i >= n4) return;
    float4 s = ((const float4*)Cp)[i];
    for (int z = 1; z < nsplit; ++z) {
        float4 v = ((const float4*)Cp)[(size_t)z * n4 + i];
        s.x += v.x; s.y += v.y; s.z += v.z; s.w += v.w;
    }
    ((float4*)out)[i] = s;
}

// ---------------------------------------------------------------------------
// Reduce 2 split-K partials + cosine scaling -> sim
// ---------------------------------------------------------------------------
__global__ __launch_bounds__(256)
void reduce_scale_kernel(const float* __restrict__ Cp, const float* __restrict__ xn,
                         const float* __restrict__ kn, float* __restrict__ sim, int n4)
{
    int i = blockIdx.x * 256 + threadIdx.x;
    if (i >= n4) return;
    float4 s = ((const float4*)Cp)[i];
    float4 v = ((const float4*)Cp)[(size_t)n4 + i];
    s.x += v.x; s.y += v.y; s.z += v.z; s.w += v.w;
    const int b  = i >> 8;            // (i*4)/1024
    const int m0 = (i * 4) & 1023;
    const float sb = 1.f / fmaxf(xn[b], EPSF);
    s.x = s.x * sb / fmaxf(kn[m0 + 0], EPSF);
    s.y = s.y * sb / fmaxf(kn[m0 + 1], EPSF);
    s.z = s.z * sb / fmaxf(kn[m0 + 2], EPSF);
    s.w = s.w * sb / fmaxf(kn[m0 + 3], EPSF);
    ((float4*)sim)[i] = s;
}

// ---------------------------------------------------------------------------
// Row L2-norm: out[row] = sqrt(sum_c X[row,c]^2), ncols = 1024.
// ---------------------------------------------------------------------------
__global__ __launch_bounds__(256)
void rownorm_kernel(const float* __restrict__ X, float* __restrict__ out, int ncols)
{
    const int row = blockIdx.x;
    const float* p = X + (size_t)row * ncols;
    float s = 0.f;
    for (int c = threadIdx.x * 4; c < ncols; c += 256 * 4) {
        float4 v = *(const float4*)(p + c);
        s += v.x * v.x + v.y * v.y + v.z * v.z + v.w * v.w;
    }
    #pragma unroll
    for (int off = 32; off > 0; off >>= 1) s += __shfl_down(s, off, 64);
    __shared__ float wsum[4];
    const int lane = threadIdx.x & 63, wwid = threadIdx.x >> 6;
    if (lane == 0) wsum[wwid] = s;
    __syncthreads();
    if (threadIdx.x == 0)
        out[row] = sqrtf(wsum[0] + wsum[1] + wsum[2] + wsum[3]);
}

// ---------------------------------------------------------------------------
// Top-4: one wave per row. Lane-local top-4 over 16 strided elems, then
// butterfly merge. (value, -index) lexicographic order = lax.top_k semantics.
// ---------------------------------------------------------------------------
__device__ inline bool tk_better(float x, int ix, float y, int iy) {
    return (x > y) || (x == y && ix < iy);
}
__device__ inline void tk_insert(float (&v)[4], int (&id)[4], float x, int m) {
    if (tk_better(x, m, v[3], id[3])) {
        v[3] = x; id[3] = m;
        if (tk_better(v[3], id[3], v[2], id[2])) {
            float tv = v[2]; int ti = id[2]; v[2] = v[3]; id[2] = id[3]; v[3] = tv; id[3] = ti;
            if (tk_better(v[2], id[2], v[1], id[1])) {
                tv = v[1]; ti = id[1]; v[1] = v[2]; id[1] = id[2]; v[2] = tv; id[2] = ti;
                if (tk_better(v[1], id[1], v[0], id[0])) {
                    tv = v[0]; ti = id[0]; v[0] = v[1]; id[0] = id[1]; v[1] = tv; id[1] = ti;
                }
            }
        }
    }
}
__global__ __launch_bounds__(64)
void topk_kernel(const float* __restrict__ sim, int* __restrict__ topi,
                 float* __restrict__ topv)
{
    const int b = blockIdx.x;
    const int lane = threadIdx.x;
    const float* row = sim + (size_t)b * MDIM;
    float v[4] = {-INFINITY, -INFINITY, -INFINITY, -INFINITY};
    int id[4] = {-1, -1, -1, -1};
    for (int j = 0; j < MDIM / 64; ++j) {
        int m = j * 64 + lane;
        tk_insert(v, id, row[m], m);
    }
    for (int off = 32; off >= 1; off >>= 1) {
        float pv[4]; int pi[4];
        #pragma unroll
        for (int q = 0; q < 4; ++q) {
            pv[q] = __shfl_xor(v[q], off, 64);
            pi[q] = __shfl_xor(id[q], off, 64);
        }
        #pragma unroll
        for (int q = 0; q < 4; ++q) tk_insert(v, id, pv[q], pi[q]);
    }
    if (lane == 0) {
        #pragma unroll
        for (int q = 0; q < 4; ++q) { topv[b * 4 + q] = v[q]; topi[b * 4 + q] = id[q]; }
    }
}

// ---------------------------------------------------------------------------
// Gather + softmax + weighted sum. One block per (b,l).
// ---------------------------------------------------------------------------
__global__ __launch_bounds__(256)
void gather_out_kernel(const float* __restrict__ pm, const int* __restrict__ topi,
                       const float* __restrict__ topv, float* __restrict__ out)
{
    const int bl = blockIdx.x;
    const int b = bl / LDIM, l = bl % LDIM;

    const int j0 = topi[b * 4 + 0], j1 = topi[b * 4 + 1], j2 = topi[b * 4 + 2], j3 = topi[b * 4 + 3];
    const float r0 = topv[b * 4 + 0], r1 = topv[b * 4 + 1], r2 = topv[b * 4 + 2], r3 = topv[b * 4 + 3];
    const float mx = fmaxf(fmaxf(r0, r1), fmaxf(r2, r3));
    const float e0 = expf(r0 - mx), e1 = expf(r1 - mx), e2 = expf(r2 - mx), e3 = expf(r3 - mx);
    const float inv = 1.f / (e0 + e1 + e2 + e3);
    const float w0 = e0 * inv, w1 = e1 * inv, w2 = e2 * inv, w3 = e3 * inv;

    const float4* p0 = (const float4*)(pm + ((size_t)j0 * LDIM + l) * EDIM);
    const float4* p1 = (const float4*)(pm + ((size_t)j1 * LDIM + l) * EDIM);
    const float4* p2 = (const float4*)(pm + ((size_t)j2 * LDIM + l) * EDIM);
    const float4* p3 = (const float4*)(pm + ((size_t)j3 * LDIM + l) * EDIM);
    float4* o = (float4*)(out + ((size_t)b * LDIM + l) * EDIM);

    for (int c = threadIdx.x; c < EDIM / 4; c += 256) {
        float4 a = p0[c], bb = p1[c], cc = p2[c], dd = p3[c];
        float4 r;
        r.x = w0 * a.x + w1 * bb.x + w2 * cc.x + w3 * dd.x;
        r.y = w0 * a.y + w1 * bb.y + w2 * cc.y + w3 * dd.y;
        r.z = w0 * a.z + w1 * bb.z + w2 * cc.z + w3 * dd.z;
        r.w = w0 * a.w + w1 * bb.w + w2 * cc.w + w3 * dd.w;
        o[c] = r;
    }
}

extern "C" void kernel_launch(void* const* d_in, const int* in_sizes, int n_in,
                              void* d_out, int out_size, void* d_ws, size_t ws_size,
                              hipStream_t stream)
{
    const float* x_query = (const float*)d_in[0];      // [B, E]
    const float* W_proj  = (const float*)d_in[1];      // [K, E]
    const float* pm      = (const float*)d_in[2];      // [M, L, E]
    const float* pkeys   = (const float*)d_in[3];      // [M, K]
    float* out = (float*)d_out;                        // [B, L, E]

    // workspace layout (byte cursor; all sizes 16B-aligned)
    char* w = (char*)d_ws;
    ushort* xq_h = (ushort*)w; w += (size_t)BDIM * EDIM * 2;   // 4 MB
    ushort* xq_l = (ushort*)w; w += (size_t)BDIM * EDIM * 2;   // 4 MB
    ushort* wp_h = (ushort*)w; w += (size_t)KDIM * EDIM * 2;   // 8 MB
    ushort* wp_l = (ushort*)w; w += (size_t)KDIM * EDIM * 2;   // 8 MB
    ushort* pk_h = (ushort*)w; w += (size_t)MDIM * KDIM * 2;   // 2 MB
    ushort* pk_l = (ushort*)w; w += (size_t)MDIM * KDIM * 2;   // 2 MB
    ushort* xp_h = (ushort*)w; w += (size_t)BDIM * KDIM * 2;   // 1 MB
    ushort* xp_l = (ushort*)w; w += (size_t)BDIM * KDIM * 2;   // 1 MB
    float* Cp1    = (float*)w; w += (size_t)4 * BDIM * KDIM * 4; // 8 MB
    float* Cp2    = (float*)w; w += (size_t)2 * BDIM * MDIM * 4; // 4 MB
    float* x_proj = (float*)w; w += (size_t)BDIM * KDIM * 4;   // 2 MB
    float* sim    = (float*)w; w += (size_t)BDIM * MDIM * 4;   // 2 MB
    float* xn     = (float*)w; w += BDIM * 4;
    float* kn     = (float*)w; w += MDIM * 4;
    float* topv   = (float*)w; w += BDIM * TOPK * 4;
    int*   topi   = (int*)w;   w += BDIM * TOPK * 4;

    // 1. split inputs to hi/lo bf16
    split_kernel<<<2048, 256, 0, stream>>>(x_query, xq_h, xq_l, BDIM * EDIM / 4);
    split_kernel<<<2048, 256, 0, stream>>>(W_proj, wp_h, wp_l, KDIM * EDIM / 4);
    split_kernel<<<1024, 256, 0, stream>>>(pkeys, pk_h, pk_l, MDIM * KDIM / 4);
    rownorm_kernel<<<MDIM, 256, 0, stream>>>(pkeys, kn, KDIM);

    // 2. x_proj = x_query @ W_proj^T  (split-K=4 partials, then reduce)
    gemm_mfma_split<<<dim3(KDIM / 64, BDIM / 64, 4), 256, 0, stream>>>(
        xq_h, xq_l, wp_h, wp_l, Cp1, BDIM, KDIM, EDIM, EDIM / 4);
    reduce4_kernel<<<BDIM * KDIM / 4 / 256, 256, 0, stream>>>(Cp1, x_proj, BDIM * KDIM / 4, 4);

    // 3. norms + split of x_proj
    rownorm_kernel<<<BDIM, 256, 0, stream>>>(x_proj, xn, KDIM);
    split_kernel<<<512, 256, 0, stream>>>(x_proj, xp_h, xp_l, BDIM * KDIM / 4);

    // 4. sim = cos(x_proj, pkeys)  (split-K=2 partials, reduce+scale)
    gemm_mfma_split<<<dim3(MDIM / 64, BDIM / 64, 2), 256, 0, stream>>>(
        xp_h, xp_l, pk_h, pk_l, Cp2, BDIM, MDIM, KDIM, KDIM / 2);
    reduce_scale_kernel<<<BDIM * MDIM / 4 / 256, 256, 0, stream>>>(
        Cp2, xn, kn, sim, BDIM * MDIM / 4);

    // 5. top-4 per row (wave per row)
    topk_kernel<<<BDIM, 64, 0, stream>>>(sim, topi, topv);

    // 6. softmax weights + gather + weighted sum -> out [512,32,4096]
    gather_out_kernel<<<BDIM * LDIM, 256, 0, stream>>>(pm, topi, topv, out);
}

// Round 4
// 241.262 us; speedup vs baseline: 2.9752x; 1.1247x over previous
//
#include <hip/hip_runtime.h>
#include <math.h>

#define BDIM 512
#define EDIM 4096
#define KDIM 1024
#define MDIM 1024
#define LDIM 32
#define TOPK 4
#define EPSF 1e-12f

typedef __attribute__((ext_vector_type(8))) short short8;
typedef __attribute__((ext_vector_type(4))) float f32x4;

struct us4 { ushort x, y, z, w; };

__device__ inline ushort f2bf_rn(float x) {
    union { float f; unsigned u; } v; v.f = x;
    unsigned r = (v.u + 0x7FFF + ((v.u >> 16) & 1)) >> 16;
    return (ushort)r;
}
__device__ inline float bf2f(ushort h) {
    union { unsigned u; float f; } v; v.u = ((unsigned)h) << 16;
    return v.f;
}

// ---------------------------------------------------------------------------
// One fused split pass for all three fp32 inputs -> (hi, lo) bf16.
// Region chosen per block (uniform branch): blocks [0,512) x_query,
// [512,1536) W_proj, [1536,1792) pkeys. Each block: 1024 float4s.
// ---------------------------------------------------------------------------
__global__ __launch_bounds__(256)
void split_all_kernel(const float* __restrict__ xq, const float* __restrict__ wp,
                      const float* __restrict__ pk,
                      ushort* __restrict__ xq_h, ushort* __restrict__ xq_l,
                      ushort* __restrict__ wp_h, ushort* __restrict__ wp_l,
                      ushort* __restrict__ pk_h, ushort* __restrict__ pk_l)
{
    const int blk = blockIdx.x;
    const float* src; ushort* hi; ushort* lo; int base;
    if (blk < 512)       { src = xq; hi = xq_h; lo = xq_l; base = blk * 1024; }
    else if (blk < 1536) { src = wp; hi = wp_h; lo = wp_l; base = (blk - 512) * 1024; }
    else                 { src = pk; hi = pk_h; lo = pk_l; base = (blk - 1536) * 1024; }

    #pragma unroll
    for (int it = 0; it < 4; ++it) {
        const int i = base + it * 256 + threadIdx.x;
        float4 v = ((const float4*)src)[i];
        us4 h, l;
        h.x = f2bf_rn(v.x); l.x = f2bf_rn(v.x - bf2f(h.x));
        h.y = f2bf_rn(v.y); l.y = f2bf_rn(v.y - bf2f(h.y));
        h.z = f2bf_rn(v.z); l.z = f2bf_rn(v.z - bf2f(h.z));
        h.w = f2bf_rn(v.w); l.w = f2bf_rn(v.w - bf2f(h.w));
        ((us4*)hi)[i] = h;
        ((us4*)lo)[i] = l;
    }
}

// ---------------------------------------------------------------------------
// Split-bf16 MFMA NT-GEMM: C = A @ B^T with A=[M][K], B=[N][K] fp32 split into
// hi/lo bf16. 3-term: ah*bh + ah*bl + al*bh (al*bl ~ 2^-18, dropped).
// 64x64 tile, BK=32, 256 threads = 4 waves of 32x32 (2x2 16x16x32 frags).
// Split-K over blockIdx.z writing partials Cp[z][M][N].
// LDS rows padded to 40 ushorts (80B): bank-quad = (5*row+g)%8 -> uniform.
// Symmetric 8-contiguous fragment loads for A and B cancel any intra-lane
// k-permutation of the MFMA operand layout; C/D map: col=lane&15,
// row=(lane>>4)*4+reg (HW-verified).
// ---------------------------------------------------------------------------
__global__ __launch_bounds__(256)
void gemm_mfma_split(const ushort* __restrict__ Ah, const ushort* __restrict__ Al,
                     const ushort* __restrict__ Bh, const ushort* __restrict__ Bl,
                     float* __restrict__ Cp, int M, int N, int K, int Kchunk)
{
    __shared__ ushort lds[4][64][40];

    const int t  = threadIdx.x;
    const int bn = blockIdx.x, bm = blockIdx.y, kz = blockIdx.z;

    const int srow = t >> 2, sg = t & 3;
    const size_t aoff = (size_t)(bm * 64 + srow) * K + sg * 8 + (size_t)kz * Kchunk;
    const size_t boff = (size_t)(bn * 64 + srow) * K + sg * 8 + (size_t)kz * Kchunk;

    const int lane = t & 63, wid = t >> 6;
    const int wr = wid >> 1, wc = wid & 1;
    const int fr = lane & 15, fg = lane >> 4;

    f32x4 acc[2][2];
    #pragma unroll
    for (int i = 0; i < 2; ++i)
        #pragma unroll
        for (int j = 0; j < 2; ++j)
            acc[i][j] = (f32x4){0.f, 0.f, 0.f, 0.f};

    for (int k0 = 0; k0 < Kchunk; k0 += 32) {
        *(short8*)(&lds[0][srow][sg * 8]) = *(const short8*)(Ah + aoff + k0);
        *(short8*)(&lds[1][srow][sg * 8]) = *(const short8*)(Al + aoff + k0);
        *(short8*)(&lds[2][srow][sg * 8]) = *(const short8*)(Bh + boff + k0);
        *(short8*)(&lds[3][srow][sg * 8]) = *(const short8*)(Bl + boff + k0);
        __syncthreads();

        short8 ah[2], al[2], bh[2], bl[2];
        #pragma unroll
        for (int i = 0; i < 2; ++i) {
            ah[i] = *(const short8*)(&lds[0][wr * 32 + i * 16 + fr][fg * 8]);
            al[i] = *(const short8*)(&lds[1][wr * 32 + i * 16 + fr][fg * 8]);
            bh[i] = *(const short8*)(&lds[2][wc * 32 + i * 16 + fr][fg * 8]);
            bl[i] = *(const short8*)(&lds[3][wc * 32 + i * 16 + fr][fg * 8]);
        }
        #pragma unroll
        for (int i = 0; i < 2; ++i)
            #pragma unroll
            for (int j = 0; j < 2; ++j) {
                acc[i][j] = __builtin_amdgcn_mfma_f32_16x16x32_bf16(ah[i], bh[j], acc[i][j], 0, 0, 0);
                acc[i][j] = __builtin_amdgcn_mfma_f32_16x16x32_bf16(ah[i], bl[j], acc[i][j], 0, 0, 0);
                acc[i][j] = __builtin_amdgcn_mfma_f32_16x16x32_bf16(al[i], bh[j], acc[i][j], 0, 0, 0);
            }
        __syncthreads();
    }

    float* Cz = Cp + (size_t)kz * M * N;
    #pragma unroll
    for (int i = 0; i < 2; ++i)
        #pragma unroll
        for (int j = 0; j < 2; ++j)
            #pragma unroll
            for (int q = 0; q < 4; ++q) {
                int orow = bm * 64 + wr * 32 + i * 16 + (lane >> 4) * 4 + q;
                int ocol = bn * 64 + wc * 32 + j * 16 + (lane & 15);
                Cz[(size_t)orow * N + ocol] = acc[i][j][q];
            }
}

// ---------------------------------------------------------------------------
// Fused: reduce split-K=4 partials of x_proj + row L2-norm + hi/lo split.
// One block per row b (K=1024 floats = 256 threads x float4). Never
// materializes fp32 x_proj in HBM.
// ---------------------------------------------------------------------------
__global__ __launch_bounds__(256)
void reduce_split_norm_kernel(const float* __restrict__ Cp,
                              ushort* __restrict__ xh, ushort* __restrict__ xl,
                              float* __restrict__ xn)
{
    const int b = blockIdx.x;
    const int i = b * 256 + threadIdx.x;       // float4 index, row = exactly 256
    const int n4 = BDIM * KDIM / 4;

    float4 s = ((const float4*)Cp)[i];
    #pragma unroll
    for (int z = 1; z < 4; ++z) {
        float4 v = ((const float4*)Cp)[(size_t)z * n4 + i];
        s.x += v.x; s.y += v.y; s.z += v.z; s.w += v.w;
    }

    us4 h, l;
    h.x = f2bf_rn(s.x); l.x = f2bf_rn(s.x - bf2f(h.x));
    h.y = f2bf_rn(s.y); l.y = f2bf_rn(s.y - bf2f(h.y));
    h.z = f2bf_rn(s.z); l.z = f2bf_rn(s.z - bf2f(h.z));
    h.w = f2bf_rn(s.w); l.w = f2bf_rn(s.w - bf2f(h.w));
    ((us4*)xh)[i] = h;
    ((us4*)xl)[i] = l;

    float sq = s.x * s.x + s.y * s.y + s.z * s.z + s.w * s.w;
    #pragma unroll
    for (int off = 32; off > 0; off >>= 1) sq += __shfl_down(sq, off, 64);
    __shared__ float wsum[4];
    const int lane = threadIdx.x & 63, wwid = threadIdx.x >> 6;
    if (lane == 0) wsum[wwid] = sq;
    __syncthreads();
    if (threadIdx.x == 0)
        xn[b] = sqrtf(wsum[0] + wsum[1] + wsum[2] + wsum[3]);
}

// ---------------------------------------------------------------------------
// Reduce 2 split-K partials + cosine scaling -> sim
// ---------------------------------------------------------------------------
__global__ __launch_bounds__(256)
void reduce_scale_kernel(const float* __restrict__ Cp, const float* __restrict__ xn,
                         const float* __restrict__ kn, float* __restrict__ sim, int n4)
{
    int i = blockIdx.x * 256 + threadIdx.x;
    if (i >= n4) return;
    float4 s = ((const float4*)Cp)[i];
    float4 v = ((const float4*)Cp)[(size_t)n4 + i];
    s.x += v.x; s.y += v.y; s.z += v.z; s.w += v.w;
    const int b  = i >> 8;
    const int m0 = (i * 4) & 1023;
    const float sb = 1.f / fmaxf(xn[b], EPSF);
    s.x = s.x * sb / fmaxf(kn[m0 + 0], EPSF);
    s.y = s.y * sb / fmaxf(kn[m0 + 1], EPSF);
    s.z = s.z * sb / fmaxf(kn[m0 + 2], EPSF);
    s.w = s.w * sb / fmaxf(kn[m0 + 3], EPSF);
    ((float4*)sim)[i] = s;
}

// ---------------------------------------------------------------------------
// Row L2-norm for prompt_keys: out[row] = sqrt(sum_c X[row,c]^2), ncols=1024.
// ---------------------------------------------------------------------------
__global__ __launch_bounds__(256)
void rownorm_kernel(const float* __restrict__ X, float* __restrict__ out, int ncols)
{
    const int row = blockIdx.x;
    const float* p = X + (size_t)row * ncols;
    float s = 0.f;
    for (int c = threadIdx.x * 4; c < ncols; c += 256 * 4) {
        float4 v = *(const float4*)(p + c);
        s += v.x * v.x + v.y * v.y + v.z * v.z + v.w * v.w;
    }
    #pragma unroll
    for (int off = 32; off > 0; off >>= 1) s += __shfl_down(s, off, 64);
    __shared__ float wsum[4];
    const int lane = threadIdx.x & 63, wwid = threadIdx.x >> 6;
    if (lane == 0) wsum[wwid] = s;
    __syncthreads();
    if (threadIdx.x == 0)
        out[row] = sqrtf(wsum[0] + wsum[1] + wsum[2] + wsum[3]);
}

// ---------------------------------------------------------------------------
// Top-4: one wave per row; butterfly merge; (value, -index) lexicographic
// order matches lax.top_k tie semantics.
// ---------------------------------------------------------------------------
__device__ inline bool tk_better(float x, int ix, float y, int iy) {
    return (x > y) || (x == y && ix < iy);
}
__device__ inline void tk_insert(float (&v)[4], int (&id)[4], float x, int m) {
    if (tk_better(x, m, v[3], id[3])) {
        v[3] = x; id[3] = m;
        if (tk_better(v[3], id[3], v[2], id[2])) {
            float tv = v[2]; int ti = id[2]; v[2] = v[3]; id[2] = id[3]; v[3] = tv; id[3] = ti;
            if (tk_better(v[2], id[2], v[1], id[1])) {
                tv = v[1]; ti = id[1]; v[1] = v[2]; id[1] = id[2]; v[2] = tv; id[2] = ti;
                if (tk_better(v[1], id[1], v[0], id[0])) {
                    tv = v[0]; ti = id[0]; v[0] = v[1]; id[0] = id[1]; v[1] = tv; id[1] = ti;
                }
            }
        }
    }
}
__global__ __launch_bounds__(64)
void topk_kernel(const float* __restrict__ sim, int* __restrict__ topi,
                 float* __restrict__ topv)
{
    const int b = blockIdx.x;
    const int lane = threadIdx.x;
    const float* row = sim + (size_t)b * MDIM;
    float v[4] = {-INFINITY, -INFINITY, -INFINITY, -INFINITY};
    int id[4] = {-1, -1, -1, -1};
    for (int j = 0; j < MDIM / 64; ++j) {
        int m = j * 64 + lane;
        tk_insert(v, id, row[m], m);
    }
    for (int off = 32; off >= 1; off >>= 1) {
        float pv[4]; int pi[4];
        #pragma unroll
        for (int q = 0; q < 4; ++q) {
            pv[q] = __shfl_xor(v[q], off, 64);
            pi[q] = __shfl_xor(id[q], off, 64);
        }
        #pragma unroll
        for (int q = 0; q < 4; ++q) tk_insert(v, id, pv[q], pi[q]);
    }
    if (lane == 0) {
        #pragma unroll
        for (int q = 0; q < 4; ++q) { topv[b * 4 + q] = v[q]; topi[b * 4 + q] = id[q]; }
    }
}

// ---------------------------------------------------------------------------
// Gather + softmax + weighted sum. (l, b)-major block order: for a fixed l
// the distinct pm slices form a ~14 MB reuse window (fits L2/L3), so the
// ~2.3x cross-batch reuse of selected prompts is served from cache instead
// of HBM. Non-temporal stores keep `out` from evicting the pm window.
// ---------------------------------------------------------------------------
__global__ __launch_bounds__(256)
void gather_out_kernel(const float* __restrict__ pm, const int* __restrict__ topi,
                       const float* __restrict__ topv, float* __restrict__ out)
{
    const int bl = blockIdx.x;
    const int b = bl & (BDIM - 1);   // (l, b)-major
    const int l = bl >> 9;

    const int j0 = topi[b * 4 + 0], j1 = topi[b * 4 + 1], j2 = topi[b * 4 + 2], j3 = topi[b * 4 + 3];
    const float r0 = topv[b * 4 + 0], r1 = topv[b * 4 + 1], r2 = topv[b * 4 + 2], r3 = topv[b * 4 + 3];
    const float mx = fmaxf(fmaxf(r0, r1), fmaxf(r2, r3));
    const float e0 = expf(r0 - mx), e1 = expf(r1 - mx), e2 = expf(r2 - mx), e3 = expf(r3 - mx);
    const float inv = 1.f / (e0 + e1 + e2 + e3);
    const float w0 = e0 * inv, w1 = e1 * inv, w2 = e2 * inv, w3 = e3 * inv;

    const f32x4* p0 = (const f32x4*)(pm + ((size_t)j0 * LDIM + l) * EDIM);
    const f32x4* p1 = (const f32x4*)(pm + ((size_t)j1 * LDIM + l) * EDIM);
    const f32x4* p2 = (const f32x4*)(pm + ((size_t)j2 * LDIM + l) * EDIM);
    const f32x4* p3 = (const f32x4*)(pm + ((size_t)j3 * LDIM + l) * EDIM);
    f32x4* o = (f32x4*)(out + ((size_t)b * LDIM + l) * EDIM);

    for (int c = threadIdx.x; c < EDIM / 4; c += 256) {
        f32x4 a = p0[c], bb = p1[c], cc = p2[c], dd = p3[c];
        f32x4 r = w0 * a + w1 * bb + w2 * cc + w3 * dd;
        __builtin_nontemporal_store(r, &o[c]);
    }
}

extern "C" void kernel_launch(void* const* d_in, const int* in_sizes, int n_in,
                              void* d_out, int out_size, void* d_ws, size_t ws_size,
                              hipStream_t stream)
{
    const float* x_query = (const float*)d_in[0];      // [B, E]
    const float* W_proj  = (const float*)d_in[1];      // [K, E]
    const float* pm      = (const float*)d_in[2];      // [M, L, E]
    const float* pkeys   = (const float*)d_in[3];      // [M, K]
    float* out = (float*)d_out;                        // [B, L, E]

    // workspace layout (byte cursor; all sizes 16B-aligned)
    char* w = (char*)d_ws;
    ushort* xq_h = (ushort*)w; w += (size_t)BDIM * EDIM * 2;
    ushort* xq_l = (ushort*)w; w += (size_t)BDIM * EDIM * 2;
    ushort* wp_h = (ushort*)w; w += (size_t)KDIM * EDIM * 2;
    ushort* wp_l = (ushort*)w; w += (size_t)KDIM * EDIM * 2;
    ushort* pk_h = (ushort*)w; w += (size_t)MDIM * KDIM * 2;
    ushort* pk_l = (ushort*)w; w += (size_t)MDIM * KDIM * 2;
    ushort* xp_h = (ushort*)w; w += (size_t)BDIM * KDIM * 2;
    ushort* xp_l = (ushort*)w; w += (size_t)BDIM * KDIM * 2;
    float* Cp1    = (float*)w; w += (size_t)4 * BDIM * KDIM * 4;
    float* Cp2    = (float*)w; w += (size_t)2 * BDIM * MDIM * 4;
    float* sim    = (float*)w; w += (size_t)BDIM * MDIM * 4;
    float* xn     = (float*)w; w += BDIM * 4;
    float* kn     = (float*)w; w += MDIM * 4;
    float* topv   = (float*)w; w += BDIM * TOPK * 4;
    int*   topi   = (int*)w;   w += BDIM * TOPK * 4;

    // 1. split all three fp32 inputs to hi/lo bf16 (one launch)
    split_all_kernel<<<1792, 256, 0, stream>>>(
        x_query, W_proj, pkeys, xq_h, xq_l, wp_h, wp_l, pk_h, pk_l);
    rownorm_kernel<<<MDIM, 256, 0, stream>>>(pkeys, kn, KDIM);

    // 2. x_proj = x_query @ W_proj^T  (split-K=4 partials)
    gemm_mfma_split<<<dim3(KDIM / 64, BDIM / 64, 4), 256, 0, stream>>>(
        xq_h, xq_l, wp_h, wp_l, Cp1, BDIM, KDIM, EDIM, EDIM / 4);

    // 3. fused reduce + rownorm + split of x_proj (one block per row)
    reduce_split_norm_kernel<<<BDIM, 256, 0, stream>>>(Cp1, xp_h, xp_l, xn);

    // 4. sim = cos(x_proj, pkeys)  (split-K=2 partials, reduce+scale)
    gemm_mfma_split<<<dim3(MDIM / 64, BDIM / 64, 2), 256, 0, stream>>>(
        xp_h, xp_l, pk_h, pk_l, Cp2, BDIM, MDIM, KDIM, KDIM / 2);
    reduce_scale_kernel<<<BDIM * MDIM / 4 / 256, 256, 0, stream>>>(
        Cp2, xn, kn, sim, BDIM * MDIM / 4);

    // 5. top-4 per row (wave per row)
    topk_kernel<<<BDIM, 64, 0, stream>>>(sim, topi, topv);

    // 6. softmax weights + gather + weighted sum -> out [512,32,4096]
    gather_out_kernel<<<BDIM * LDIM, 256, 0, stream>>>(pm, topi, topv, out);
}

// Round 5
// 240.260 us; speedup vs baseline: 2.9876x; 1.0042x over previous
//
#include <hip/hip_runtime.h>
#include <math.h>

#define BDIM 512
#define EDIM 4096
#define KDIM 1024
#define MDIM 1024
#define LDIM 32
#define TOPK 4
#define EPSF 1e-12f

typedef __attribute__((ext_vector_type(8))) short short8;
typedef __attribute__((ext_vector_type(4))) float f32x4;

struct us4 { ushort x, y, z, w; };

__device__ inline ushort f2bf_rn(float x) {
    union { float f; unsigned u; } v; v.f = x;
    unsigned r = (v.u + 0x7FFF + ((v.u >> 16) & 1)) >> 16;
    return (ushort)r;
}
__device__ inline float bf2f(ushort h) {
    union { unsigned u; float f; } v; v.u = ((unsigned)h) << 16;
    return v.f;
}

// ---------------------------------------------------------------------------
// One fused split pass for all three fp32 inputs -> (hi, lo) bf16.
// Blocks [0,512) x_query, [512,1536) W_proj, [1536,1792) pkeys.
// Each block: 1024 float4s (4 iterations x 256 threads).
// pkeys region additionally computes kn[row] (each iteration covers exactly
// one 1024-float key row; per-thread grouping + reduction order identical to
// the previous standalone rownorm kernel -> bit-identical kn).
// ---------------------------------------------------------------------------
__global__ __launch_bounds__(256)
void split_all_kernel(const float* __restrict__ xq, const float* __restrict__ wp,
                      const float* __restrict__ pk,
                      ushort* __restrict__ xq_h, ushort* __restrict__ xq_l,
                      ushort* __restrict__ wp_h, ushort* __restrict__ wp_l,
                      ushort* __restrict__ pk_h, ushort* __restrict__ pk_l,
                      float* __restrict__ kn)
{
    const int blk = blockIdx.x;
    const int t = threadIdx.x;
    const float* src; ushort* hi; ushort* lo; int base;
    bool do_norm = false; int rowbase = 0;
    if (blk < 512)       { src = xq; hi = xq_h; lo = xq_l; base = blk * 1024; }
    else if (blk < 1536) { src = wp; hi = wp_h; lo = wp_l; base = (blk - 512) * 1024; }
    else                 { src = pk; hi = pk_h; lo = pk_l; base = (blk - 1536) * 1024;
                           do_norm = true; rowbase = (blk - 1536) * 4; }

    __shared__ float wsum[4];
    const int lane = t & 63, wwid = t >> 6;

    #pragma unroll
    for (int it = 0; it < 4; ++it) {
        const int i = base + it * 256 + t;
        float4 v = ((const float4*)src)[i];
        us4 h, l;
        h.x = f2bf_rn(v.x); l.x = f2bf_rn(v.x - bf2f(h.x));
        h.y = f2bf_rn(v.y); l.y = f2bf_rn(v.y - bf2f(h.y));
        h.z = f2bf_rn(v.z); l.z = f2bf_rn(v.z - bf2f(h.z));
        h.w = f2bf_rn(v.w); l.w = f2bf_rn(v.w - bf2f(h.w));
        ((us4*)hi)[i] = h;
        ((us4*)lo)[i] = l;

        if (do_norm) {
            float sq = v.x * v.x + v.y * v.y + v.z * v.z + v.w * v.w;
            #pragma unroll
            for (int off = 32; off > 0; off >>= 1) sq += __shfl_down(sq, off, 64);
            __syncthreads();                    // WAR vs previous iteration's wsum
            if (lane == 0) wsum[wwid] = sq;
            __syncthreads();
            if (t == 0)
                kn[rowbase + it] = sqrtf(wsum[0] + wsum[1] + wsum[2] + wsum[3]);
        }
    }
}

// ---------------------------------------------------------------------------
// Split-bf16 MFMA NT-GEMM: C = A @ B^T, A=[M][K], B=[N][K] as hi/lo bf16.
// 3-term: ah*bh + ah*bl + al*bh (al*bl ~ 2^-18, dropped).
// 64x64 tile, BK=32, 256 threads = 4 waves of 32x32 (2x2 16x16x32 frags).
// Split-K over blockIdx.z writing partials Cp[z][M][N].
// Register prefetch of next k-chunk issued right after the barrier so the
// global-load latency hides under fragment reads + 12 MFMAs (math order
// unchanged -> bit-identical results to the unpipelined version).
// ---------------------------------------------------------------------------
__global__ __launch_bounds__(256)
void gemm_mfma_split(const ushort* __restrict__ Ah, const ushort* __restrict__ Al,
                     const ushort* __restrict__ Bh, const ushort* __restrict__ Bl,
                     float* __restrict__ Cp, int M, int N, int K, int Kchunk)
{
    __shared__ ushort lds[4][64][40];

    const int t  = threadIdx.x;
    const int bn = blockIdx.x, bm = blockIdx.y, kz = blockIdx.z;

    const int srow = t >> 2, sg = t & 3;
    const size_t aoff = (size_t)(bm * 64 + srow) * K + sg * 8 + (size_t)kz * Kchunk;
    const size_t boff = (size_t)(bn * 64 + srow) * K + sg * 8 + (size_t)kz * Kchunk;

    const int lane = t & 63, wid = t >> 6;
    const int wr = wid >> 1, wc = wid & 1;
    const int fr = lane & 15, fg = lane >> 4;

    f32x4 acc[2][2];
    #pragma unroll
    for (int i = 0; i < 2; ++i)
        #pragma unroll
        for (int j = 0; j < 2; ++j)
            acc[i][j] = (f32x4){0.f, 0.f, 0.f, 0.f};

    short8 pA0 = *(const short8*)(Ah + aoff);
    short8 pA1 = *(const short8*)(Al + aoff);
    short8 pB0 = *(const short8*)(Bh + boff);
    short8 pB1 = *(const short8*)(Bl + boff);

    for (int k0 = 0; k0 < Kchunk; k0 += 32) {
        *(short8*)(&lds[0][srow][sg * 8]) = pA0;
        *(short8*)(&lds[1][srow][sg * 8]) = pA1;
        *(short8*)(&lds[2][srow][sg * 8]) = pB0;
        *(short8*)(&lds[3][srow][sg * 8]) = pB1;
        __syncthreads();

        if (k0 + 32 < Kchunk) {                 // prefetch next chunk (in flight
            pA0 = *(const short8*)(Ah + aoff + k0 + 32);   // during frag reads+MFMA)
            pA1 = *(const short8*)(Al + aoff + k0 + 32);
            pB0 = *(const short8*)(Bh + boff + k0 + 32);
            pB1 = *(const short8*)(Bl + boff + k0 + 32);
        }

        short8 ah[2], al[2], bh[2], bl[2];
        #pragma unroll
        for (int i = 0; i < 2; ++i) {
            ah[i] = *(const short8*)(&lds[0][wr * 32 + i * 16 + fr][fg * 8]);
            al[i] = *(const short8*)(&lds[1][wr * 32 + i * 16 + fr][fg * 8]);
            bh[i] = *(const short8*)(&lds[2][wc * 32 + i * 16 + fr][fg * 8]);
            bl[i] = *(const short8*)(&lds[3][wc * 32 + i * 16 + fr][fg * 8]);
        }
        #pragma unroll
        for (int i = 0; i < 2; ++i)
            #pragma unroll
            for (int j = 0; j < 2; ++j) {
                acc[i][j] = __builtin_amdgcn_mfma_f32_16x16x32_bf16(ah[i], bh[j], acc[i][j], 0, 0, 0);
                acc[i][j] = __builtin_amdgcn_mfma_f32_16x16x32_bf16(ah[i], bl[j], acc[i][j], 0, 0, 0);
                acc[i][j] = __builtin_amdgcn_mfma_f32_16x16x32_bf16(al[i], bh[j], acc[i][j], 0, 0, 0);
            }
        __syncthreads();
    }

    float* Cz = Cp + (size_t)kz * M * N;
    #pragma unroll
    for (int i = 0; i < 2; ++i)
        #pragma unroll
        for (int j = 0; j < 2; ++j)
            #pragma unroll
            for (int q = 0; q < 4; ++q) {
                int orow = bm * 64 + wr * 32 + i * 16 + (lane >> 4) * 4 + q;
                int ocol = bn * 64 + wc * 32 + j * 16 + (lane & 15);
                Cz[(size_t)orow * N + ocol] = acc[i][j][q];
            }
}

// ---------------------------------------------------------------------------
// Fused: reduce split-K=4 partials of x_proj + row L2-norm + hi/lo split.
// One block per row b (K=1024 floats = 256 threads x float4).
// ---------------------------------------------------------------------------
__global__ __launch_bounds__(256)
void reduce_split_norm_kernel(const float* __restrict__ Cp,
                              ushort* __restrict__ xh, ushort* __restrict__ xl,
                              float* __restrict__ xn)
{
    const int b = blockIdx.x;
    const int i = b * 256 + threadIdx.x;
    const int n4 = BDIM * KDIM / 4;

    float4 s = ((const float4*)Cp)[i];
    #pragma unroll
    for (int z = 1; z < 4; ++z) {
        float4 v = ((const float4*)Cp)[(size_t)z * n4 + i];
        s.x += v.x; s.y += v.y; s.z += v.z; s.w += v.w;
    }

    us4 h, l;
    h.x = f2bf_rn(s.x); l.x = f2bf_rn(s.x - bf2f(h.x));
    h.y = f2bf_rn(s.y); l.y = f2bf_rn(s.y - bf2f(h.y));
    h.z = f2bf_rn(s.z); l.z = f2bf_rn(s.z - bf2f(h.z));
    h.w = f2bf_rn(s.w); l.w = f2bf_rn(s.w - bf2f(h.w));
    ((us4*)xh)[i] = h;
    ((us4*)xl)[i] = l;

    float sq = s.x * s.x + s.y * s.y + s.z * s.z + s.w * s.w;
    #pragma unroll
    for (int off = 32; off > 0; off >>= 1) sq += __shfl_down(sq, off, 64);
    __shared__ float wsum[4];
    const int lane = threadIdx.x & 63, wwid = threadIdx.x >> 6;
    if (lane == 0) wsum[wwid] = sq;
    __syncthreads();
    if (threadIdx.x == 0)
        xn[b] = sqrtf(wsum[0] + wsum[1] + wsum[2] + wsum[3]);
}

// ---------------------------------------------------------------------------
// Fused reduce(2 split-K partials) + cosine scale + top-4. One wave per row.
// Per-element math identical in op order to the previous reduce_scale kernel:
// s = (cp0 + cp1) * sb / fmax(kn[m], eps)  -> bit-identical selection.
// ---------------------------------------------------------------------------
__device__ inline bool tk_better(float x, int ix, float y, int iy) {
    return (x > y) || (x == y && ix < iy);
}
__device__ inline void tk_insert(float (&v)[4], int (&id)[4], float x, int m) {
    if (tk_better(x, m, v[3], id[3])) {
        v[3] = x; id[3] = m;
        if (tk_better(v[3], id[3], v[2], id[2])) {
            float tv = v[2]; int ti = id[2]; v[2] = v[3]; id[2] = id[3]; v[3] = tv; id[3] = ti;
            if (tk_better(v[2], id[2], v[1], id[1])) {
                tv = v[1]; ti = id[1]; v[1] = v[2]; id[1] = id[2]; v[2] = tv; id[2] = ti;
                if (tk_better(v[1], id[1], v[0], id[0])) {
                    tv = v[0]; ti = id[0]; v[0] = v[1]; id[0] = id[1]; v[1] = tv; id[1] = ti;
                }
            }
        }
    }
}
__global__ __launch_bounds__(64)
void topk_scale_kernel(const float* __restrict__ Cp2, const float* __restrict__ xn,
                       const float* __restrict__ kn,
                       int* __restrict__ topi, float* __restrict__ topv)
{
    const int b = blockIdx.x;
    const int lane = threadIdx.x;
    const float sb = 1.f / fmaxf(xn[b], EPSF);
    const float* r0 = Cp2 + (size_t)b * MDIM;
    const float* r1 = Cp2 + (size_t)BDIM * MDIM + (size_t)b * MDIM;

    float v[4] = {-INFINITY, -INFINITY, -INFINITY, -INFINITY};
    int id[4] = {-1, -1, -1, -1};
    for (int j = 0; j < MDIM / 64; ++j) {
        int m = j * 64 + lane;
        float s = (r0[m] + r1[m]) * sb / fmaxf(kn[m], EPSF);
        tk_insert(v, id, s, m);
    }
    for (int off = 32; off >= 1; off >>= 1) {
        float pv[4]; int pi[4];
        #pragma unroll
        for (int q = 0; q < 4; ++q) {
            pv[q] = __shfl_xor(v[q], off, 64);
            pi[q] = __shfl_xor(id[q], off, 64);
        }
        #pragma unroll
        for (int q = 0; q < 4; ++q) tk_insert(v, id, pv[q], pi[q]);
    }
    if (lane == 0) {
        #pragma unroll
        for (int q = 0; q < 4; ++q) { topv[b * 4 + q] = v[q]; topi[b * 4 + q] = id[q]; }
    }
}

// ---------------------------------------------------------------------------
// Gather + softmax + weighted sum. (l, b)-major block order keeps the per-l
// distinct-pm window (~14 MB) L2/L3-resident; non-temporal stores keep `out`
// from evicting it.
// ---------------------------------------------------------------------------
__global__ __launch_bounds__(256)
void gather_out_kernel(const float* __restrict__ pm, const int* __restrict__ topi,
                       const float* __restrict__ topv, float* __restrict__ out)
{
    const int bl = blockIdx.x;
    const int b = bl & (BDIM - 1);   // (l, b)-major
    const int l = bl >> 9;

    const int j0 = topi[b * 4 + 0], j1 = topi[b * 4 + 1], j2 = topi[b * 4 + 2], j3 = topi[b * 4 + 3];
    const float r0 = topv[b * 4 + 0], r1 = topv[b * 4 + 1], r2 = topv[b * 4 + 2], r3 = topv[b * 4 + 3];
    const float mx = fmaxf(fmaxf(r0, r1), fmaxf(r2, r3));
    const float e0 = expf(r0 - mx), e1 = expf(r1 - mx), e2 = expf(r2 - mx), e3 = expf(r3 - mx);
    const float inv = 1.f / (e0 + e1 + e2 + e3);
    const float w0 = e0 * inv, w1 = e1 * inv, w2 = e2 * inv, w3 = e3 * inv;

    const f32x4* p0 = (const f32x4*)(pm + ((size_t)j0 * LDIM + l) * EDIM);
    const f32x4* p1 = (const f32x4*)(pm + ((size_t)j1 * LDIM + l) * EDIM);
    const f32x4* p2 = (const f32x4*)(pm + ((size_t)j2 * LDIM + l) * EDIM);
    const f32x4* p3 = (const f32x4*)(pm + ((size_t)j3 * LDIM + l) * EDIM);
    f32x4* o = (f32x4*)(out + ((size_t)b * LDIM + l) * EDIM);

    for (int c = threadIdx.x; c < EDIM / 4; c += 256) {
        f32x4 a = p0[c], bb = p1[c], cc = p2[c], dd = p3[c];
        f32x4 r = w0 * a + w1 * bb + w2 * cc + w3 * dd;
        __builtin_nontemporal_store(r, &o[c]);
    }
}

extern "C" void kernel_launch(void* const* d_in, const int* in_sizes, int n_in,
                              void* d_out, int out_size, void* d_ws, size_t ws_size,
                              hipStream_t stream)
{
    const float* x_query = (const float*)d_in[0];      // [B, E]
    const float* W_proj  = (const float*)d_in[1];      // [K, E]
    const float* pm      = (const float*)d_in[2];      // [M, L, E]
    const float* pkeys   = (const float*)d_in[3];      // [M, K]
    float* out = (float*)d_out;                        // [B, L, E]

    // workspace layout (byte cursor; all sizes 16B-aligned)
    char* w = (char*)d_ws;
    ushort* xq_h = (ushort*)w; w += (size_t)BDIM * EDIM * 2;
    ushort* xq_l = (ushort*)w; w += (size_t)BDIM * EDIM * 2;
    ushort* wp_h = (ushort*)w; w += (size_t)KDIM * EDIM * 2;
    ushort* wp_l = (ushort*)w; w += (size_t)KDIM * EDIM * 2;
    ushort* pk_h = (ushort*)w; w += (size_t)MDIM * KDIM * 2;
    ushort* pk_l = (ushort*)w; w += (size_t)MDIM * KDIM * 2;
    ushort* xp_h = (ushort*)w; w += (size_t)BDIM * KDIM * 2;
    ushort* xp_l = (ushort*)w; w += (size_t)BDIM * KDIM * 2;
    float* Cp1    = (float*)w; w += (size_t)4 * BDIM * KDIM * 4;
    float* Cp2    = (float*)w; w += (size_t)2 * BDIM * MDIM * 4;
    float* xn     = (float*)w; w += BDIM * 4;
    float* kn     = (float*)w; w += MDIM * 4;
    float* topv   = (float*)w; w += BDIM * TOPK * 4;
    int*   topi   = (int*)w;   w += BDIM * TOPK * 4;

    // 1. split all three fp32 inputs to hi/lo bf16 + pkeys row norms
    split_all_kernel<<<1792, 256, 0, stream>>>(
        x_query, W_proj, pkeys, xq_h, xq_l, wp_h, wp_l, pk_h, pk_l, kn);

    // 2. x_proj = x_query @ W_proj^T  (split-K=4 partials)
    gemm_mfma_split<<<dim3(KDIM / 64, BDIM / 64, 4), 256, 0, stream>>>(
        xq_h, xq_l, wp_h, wp_l, Cp1, BDIM, KDIM, EDIM, EDIM / 4);

    // 3. fused reduce + rownorm + split of x_proj (one block per row)
    reduce_split_norm_kernel<<<BDIM, 256, 0, stream>>>(Cp1, xp_h, xp_l, xn);

    // 4. sim partials (split-K=2)
    gemm_mfma_split<<<dim3(MDIM / 64, BDIM / 64, 2), 256, 0, stream>>>(
        xp_h, xp_l, pk_h, pk_l, Cp2, BDIM, MDIM, KDIM, KDIM / 2);

    // 5. fused reduce + cosine scale + top-4 (one wave per row)
    topk_scale_kernel<<<BDIM, 64, 0, stream>>>(Cp2, xn, kn, topi, topv);

    // 6. softmax weights + gather + weighted sum -> out [512,32,4096]
    gather_out_kernel<<<BDIM * LDIM, 256, 0, stream>>>(pm, topi, topv, out);
}